// Round 1
// baseline (131.351 us; speedup 1.0000x reference)
//
#include <hip/hip_runtime.h>
#include <stdint.h>

// ---------- types & helpers ----------
typedef __attribute__((ext_vector_type(8))) short bf16x8;   // 8 bf16 (4 VGPRs)
typedef __attribute__((ext_vector_type(4))) float f32x4;    // MFMA accum

#define AS1 __attribute__((address_space(1)))
#define AS3 __attribute__((address_space(3)))

__device__ __forceinline__ void gload_lds16(const void* g, void* l){
  __builtin_amdgcn_global_load_lds((AS1 void*)g, (AS3 void*)l, 16, 0, 0);
}

__device__ __forceinline__ unsigned short to_bf16(float f){
  union { float f; unsigned int i; } x; x.f = f;
  unsigned int u = x.i;
  unsigned int r = (u + 0x7fffu + ((u >> 16) & 1u)) >> 16;   // RNE
  return (unsigned short)r;
}
__device__ __forceinline__ float bf2f(unsigned short s){
  union { unsigned int i; float f; } x; x.i = ((unsigned int)s) << 16; return x.f;
}
__device__ __forceinline__ float bflo(unsigned int u){
  union { unsigned int i; float f; } x; x.i = u << 16; return x.f;
}
__device__ __forceinline__ float bfhi(unsigned int u){
  union { unsigned int i; float f; } x; x.i = u & 0xffff0000u; return x.f;
}
__device__ __forceinline__ void unp8(uint4 v, float* f){
  f[0]=bflo(v.x); f[1]=bfhi(v.x); f[2]=bflo(v.y); f[3]=bfhi(v.y);
  f[4]=bflo(v.z); f[5]=bfhi(v.z); f[6]=bflo(v.w); f[7]=bfhi(v.w);
}

// ---------- K0a: cast weights to bf16 ----------
__global__ void cast_w_kernel(const float* __restrict__ qkv_w, const float* __restrict__ proj_w,
                              unsigned short* __restrict__ wq, unsigned short* __restrict__ wp){
  int i = blockIdx.x * 256 + threadIdx.x;
  const int nq = 768 * 256;
  const int np = 256 * 256;
  if (i < nq)           wq[i]      = to_bf16(qkv_w[i]);
  else if (i < nq + np) wp[i - nq] = to_bf16(proj_w[i - nq]);
}

// ---------- K0b: transpose+cast x (b,c,l) fp32 -> xb (b,l,c) bf16 ----------
__global__ __launch_bounds__(256) void tcast_kernel(const float* __restrict__ x,
                                                    unsigned short* __restrict__ xb){
  __shared__ float tile[64][65];
  int b  = blockIdx.z;
  int c0 = blockIdx.y * 64;
  int l0 = blockIdx.x * 64;
  int tid = threadIdx.x;
  const float* xp = x + ((size_t)b * 256 + c0) * 4096 + l0;
  #pragma unroll
  for (int rep = 0; rep < 16; rep++){
    int idx = rep * 256 + tid;
    int cl = idx >> 6, ll = idx & 63;
    tile[cl][ll] = xp[(size_t)cl * 4096 + ll];
  }
  __syncthreads();
  unsigned short* op = xb + ((size_t)b * 4096 + l0) * 256 + c0;
  #pragma unroll
  for (int rep = 0; rep < 16; rep++){
    int idx = rep * 256 + tid;
    int ll = idx >> 6, cl = idx & 63;
    op[(size_t)ll * 256 + cl] = to_bf16(tile[cl][ll]);
  }
}

// ---------- K1: QKV GEMM  D[o][l] = sum_c Wq[o][c]*X[l][c] (+bias) ----------
// A = Wq [768][256] bf16, B = xb[b] [4096][256] bf16 (both K-contiguous rows)
// out: qkv [b][o>>5][l][o&31] bf16
__global__ __launch_bounds__(256, 2) void qkv_gemm_kernel(
    const unsigned short* __restrict__ Wq, const unsigned short* __restrict__ xb,
    const float* __restrict__ qkv_b, unsigned short* __restrict__ qkv){
  __shared__ __align__(16) unsigned short lA[128 * 64];
  __shared__ __align__(16) unsigned short lB[128 * 64];
  int b      = blockIdx.y;
  int tile_m = blockIdx.x % 6;
  int tile_n = blockIdx.x / 6;
  int tid  = threadIdx.x;
  int lane = tid & 63;
  int wave = tid >> 6;
  int m_w = (wave >> 1) * 64;
  int n_w = (wave & 1) * 64;

  f32x4 zero; zero[0]=0.f; zero[1]=0.f; zero[2]=0.f; zero[3]=0.f;
  f32x4 acc[4][4];
  #pragma unroll
  for (int i = 0; i < 4; i++){
    #pragma unroll
    for (int j = 0; j < 4; j++) acc[i][j] = zero;
  }

  const unsigned short* Abase = Wq + (size_t)tile_m * 128 * 256;
  const unsigned short* Bbase = xb + ((size_t)b * 4096 + (size_t)tile_n * 128) * 256;

  for (int ks = 0; ks < 4; ks++){
    int k0 = ks * 64;
    // stage 128x64 bf16 tiles; LDS dest is linear, global source column-block is
    // XOR-pre-swizzled so ds_read with the same XOR is bank-conflict-reduced.
    #pragma unroll
    for (int inst = 0; inst < 4; inst++){
      int u    = inst * 256 + tid;      // 16B unit index within tile
      int row  = u >> 3;                // 8 x 16B per 128B row
      int col  = u & 7;
      int scol = col ^ (row & 7);
      unsigned short* ld = lA + inst * 2048 + wave * 512;   // wave-uniform base
      gload_lds16(Abase + (size_t)row * 256 + k0 + scol * 8, ld);
      unsigned short* ldb = lB + inst * 2048 + wave * 512;
      gload_lds16(Bbase + (size_t)row * 256 + k0 + scol * 8, ldb);
    }
    __syncthreads();
    #pragma unroll
    for (int kk = 0; kk < 2; kk++){
      bf16x8 ar[4], br[4];
      #pragma unroll
      for (int i = 0; i < 4; i++){
        int rowa = m_w + i * 16 + (lane & 15);
        int slot = kk * 4 + (lane >> 4);
        ar[i] = *(const bf16x8*)((const char*)lA + rowa * 128 + ((slot ^ (rowa & 7)) << 4));
        int rowb = n_w + i * 16 + (lane & 15);
        br[i] = *(const bf16x8*)((const char*)lB + rowb * 128 + ((slot ^ (rowb & 7)) << 4));
      }
      #pragma unroll
      for (int i = 0; i < 4; i++){
        #pragma unroll
        for (int j = 0; j < 4; j++)
          acc[i][j] = __builtin_amdgcn_mfma_f32_16x16x32_bf16(ar[i], br[j], acc[i][j], 0, 0, 0);
      }
    }
    __syncthreads();
  }

  // epilogue: D row m = o, col n = l ; o -> [b][o>>5][l][o&31]
  #pragma unroll
  for (int i = 0; i < 4; i++){
    #pragma unroll
    for (int j = 0; j < 4; j++){
      int l = tile_n * 128 + n_w + j * 16 + (lane & 15);
      #pragma unroll
      for (int r = 0; r < 4; r++){
        int o = tile_m * 128 + m_w + i * 16 + ((lane >> 4) << 2) + r;
        float v = acc[i][j][r] + qkv_b[o];
        qkv[((size_t)(b * 24 + (o >> 5)) * 4096 + l) * 32 + (o & 31)] = to_bf16(v);
      }
    }
  }
}

// ---------- K2: multi-dilation local attention ----------
// qkv [b][g][l][32], g = s*8 + dil*2 + head ; out stk [b][l][dil][head*32+c] bf16
__global__ __launch_bounds__(256) void attn_kernel(
    const unsigned short* __restrict__ qkv, unsigned short* __restrict__ stk){
  int tid = threadIdx.x;
  int l   = blockIdx.x * 256 + tid;
  int b   = blockIdx.y;
  int di  = blockIdx.z;
  int dil = 1 << di;
  int yy = l >> 6, xx = l & 63;

  #pragma unroll
  for (int head = 0; head < 2; head++){
    size_t gq = ((size_t)(b * 24 +      di * 2 + head) * 4096 + l) * 32;
    size_t gk = ((size_t)(b * 24 +  8 + di * 2 + head) * 4096) * 32;
    size_t gv = ((size_t)(b * 24 + 16 + di * 2 + head) * 4096) * 32;
    float q[32];
    {
      const uint4* p = (const uint4*)(qkv + gq);
      unp8(p[0], q); unp8(p[1], q + 8); unp8(p[2], q + 16); unp8(p[3], q + 24);
    }
    float sc[9]; int nidx[9]; bool ib[9];
    #pragma unroll
    for (int p = 0; p < 9; p++){
      int ny = yy + (p / 3 - 1) * dil;
      int nx = xx + (p % 3 - 1) * dil;
      bool in = ((unsigned)ny < 64u) && ((unsigned)nx < 64u);
      ib[p] = in; nidx[p] = ny * 64 + nx;
      float dot = 0.f;
      if (in){
        const uint4* kp = (const uint4*)(qkv + gk + (size_t)nidx[p] * 32);
        #pragma unroll
        for (int g = 0; g < 4; g++){
          float kf[8]; unp8(kp[g], kf);
          #pragma unroll
          for (int c = 0; c < 8; c++) dot += q[g * 8 + c] * kf[c];
        }
      }
      sc[p] = dot * 0.17677669529663687f;   // HEAD_DIM^-0.5 ; OOB -> exactly 0 (zero-pad)
    }
    float mx = sc[0];
    #pragma unroll
    for (int p = 1; p < 9; p++) mx = fmaxf(mx, sc[p]);
    float w[9]; float den = 0.f;
    #pragma unroll
    for (int p = 0; p < 9; p++){ w[p] = __expf(sc[p] - mx); den += w[p]; }
    float inv = 1.f / den;                   // OOB taps stay in the denominator (zero-pad semantics)
    float o[32];
    #pragma unroll
    for (int c = 0; c < 32; c++) o[c] = 0.f;
    #pragma unroll
    for (int p = 0; p < 9; p++){
      if (ib[p]){
        float wp = w[p] * inv;
        const uint4* vp = (const uint4*)(qkv + gv + (size_t)nidx[p] * 32);
        #pragma unroll
        for (int g = 0; g < 4; g++){
          float vf[8]; unp8(vp[g], vf);
          #pragma unroll
          for (int c = 0; c < 8; c++) o[g * 8 + c] += wp * vf[c];
        }
      }
    }
    unsigned short* op = stk + ((size_t)(b * 4096 + l) * 4 + di) * 64 + head * 32;
    #pragma unroll
    for (int g = 0; g < 4; g++){
      uint4 u;
      u.x = (unsigned)to_bf16(o[g*8+0]) | ((unsigned)to_bf16(o[g*8+1]) << 16);
      u.y = (unsigned)to_bf16(o[g*8+2]) | ((unsigned)to_bf16(o[g*8+3]) << 16);
      u.z = (unsigned)to_bf16(o[g*8+4]) | ((unsigned)to_bf16(o[g*8+5]) << 16);
      u.w = (unsigned)to_bf16(o[g*8+6]) | ((unsigned)to_bf16(o[g*8+7]) << 16);
      ((uint4*)op)[g] = u;
    }
  }
}

// ---------- K3: fc(4x4)+residual+LayerNorm(64) ; 1 wave = 1 pixel ----------
__global__ __launch_bounds__(256) void fcln_kernel(
    const unsigned short* __restrict__ stk,
    const float* __restrict__ fc_w, const float* __restrict__ fc_b,
    const float* __restrict__ ln_g, const float* __restrict__ ln_b,
    unsigned short* __restrict__ y2){
  int tid = threadIdx.x;
  int pix = blockIdx.x * 4 + (tid >> 6);
  int c   = tid & 63;
  const unsigned short* sp = stk + (size_t)pix * 256;
  float st[4];
  #pragma unroll
  for (int s = 0; s < 4; s++) st[s] = bf2f(sp[s * 64 + c]);
  float fused[4];
  #pragma unroll
  for (int t = 0; t < 4; t++){
    float f = fc_b[t] + st[t];
    #pragma unroll
    for (int s = 0; s < 4; s++) f += fc_w[t * 4 + s] * st[s];
    fused[t] = f;
  }
  float g = ln_g[c], bb = ln_b[c];
  unsigned short* op = y2 + (size_t)pix * 256;
  #pragma unroll
  for (int t = 0; t < 4; t++){
    float v = fused[t];
    float s1 = v, s2 = v * v;
    #pragma unroll
    for (int m = 1; m < 64; m <<= 1){ s1 += __shfl_xor(s1, m); s2 += __shfl_xor(s2, m); }
    float mu  = s1 * 0.015625f;
    float var = s2 * 0.015625f - mu * mu;
    float rs  = rsqrtf(var + 1e-5f);
    op[t * 64 + c] = to_bf16((v - mu) * rs * g + bb);
  }
}

// ---------- K4: proj GEMM  out[b][o][l] = sum_ch Wp[o][ch]*y2[b][l][ch] + pb ----------
__global__ __launch_bounds__(256, 2) void proj_gemm_kernel(
    const unsigned short* __restrict__ Wp, const unsigned short* __restrict__ y2,
    const float* __restrict__ proj_b, float* __restrict__ out){
  __shared__ __align__(16) unsigned short lA[128 * 64];
  __shared__ __align__(16) unsigned short lB[128 * 64];
  int b      = blockIdx.y;
  int tile_m = blockIdx.x & 1;
  int tile_n = blockIdx.x >> 1;
  int tid  = threadIdx.x;
  int lane = tid & 63;
  int wave = tid >> 6;
  int m_w = (wave >> 1) * 64;
  int n_w = (wave & 1) * 64;

  f32x4 zero; zero[0]=0.f; zero[1]=0.f; zero[2]=0.f; zero[3]=0.f;
  f32x4 acc[4][4];
  #pragma unroll
  for (int i = 0; i < 4; i++){
    #pragma unroll
    for (int j = 0; j < 4; j++) acc[i][j] = zero;
  }

  const unsigned short* Abase = Wp + (size_t)tile_m * 128 * 256;
  const unsigned short* Bbase = y2 + ((size_t)b * 4096 + (size_t)tile_n * 128) * 256;

  for (int ks = 0; ks < 4; ks++){
    int k0 = ks * 64;
    #pragma unroll
    for (int inst = 0; inst < 4; inst++){
      int u    = inst * 256 + tid;
      int row  = u >> 3;
      int col  = u & 7;
      int scol = col ^ (row & 7);
      unsigned short* ld = lA + inst * 2048 + wave * 512;
      gload_lds16(Abase + (size_t)row * 256 + k0 + scol * 8, ld);
      unsigned short* ldb = lB + inst * 2048 + wave * 512;
      gload_lds16(Bbase + (size_t)row * 256 + k0 + scol * 8, ldb);
    }
    __syncthreads();
    #pragma unroll
    for (int kk = 0; kk < 2; kk++){
      bf16x8 ar[4], br[4];
      #pragma unroll
      for (int i = 0; i < 4; i++){
        int rowa = m_w + i * 16 + (lane & 15);
        int slot = kk * 4 + (lane >> 4);
        ar[i] = *(const bf16x8*)((const char*)lA + rowa * 128 + ((slot ^ (rowa & 7)) << 4));
        int rowb = n_w + i * 16 + (lane & 15);
        br[i] = *(const bf16x8*)((const char*)lB + rowb * 128 + ((slot ^ (rowb & 7)) << 4));
      }
      #pragma unroll
      for (int i = 0; i < 4; i++){
        #pragma unroll
        for (int j = 0; j < 4; j++)
          acc[i][j] = __builtin_amdgcn_mfma_f32_16x16x32_bf16(ar[i], br[j], acc[i][j], 0, 0, 0);
      }
    }
    __syncthreads();
  }

  #pragma unroll
  for (int i = 0; i < 4; i++){
    #pragma unroll
    for (int j = 0; j < 4; j++){
      int l = tile_n * 128 + n_w + j * 16 + (lane & 15);
      #pragma unroll
      for (int r = 0; r < 4; r++){
        int o = tile_m * 128 + m_w + i * 16 + ((lane >> 4) << 2) + r;
        out[((size_t)b * 256 + o) * 4096 + l] = acc[i][j][r] + proj_b[o];
      }
    }
  }
}

// ---------- launch ----------
extern "C" void kernel_launch(void* const* d_in, const int* in_sizes, int n_in,
                              void* d_out, int out_size, void* d_ws, size_t ws_size,
                              hipStream_t stream){
  const float* x      = (const float*)d_in[0];
  const float* qkv_w  = (const float*)d_in[1];
  const float* qkv_b  = (const float*)d_in[2];
  const float* fc_w   = (const float*)d_in[3];
  const float* fc_b   = (const float*)d_in[4];
  const float* ln_g   = (const float*)d_in[5];
  const float* ln_b   = (const float*)d_in[6];
  const float* proj_w = (const float*)d_in[7];
  const float* proj_b = (const float*)d_in[8];
  float* out = (float*)d_out;

  // workspace layout (bf16 elements)
  unsigned short* xb  = (unsigned short*)d_ws;            // 8*4096*256  = 8,388,608
  unsigned short* qkv = xb  + (size_t)8 * 4096 * 256;     // 8*24*4096*32 = 25,165,824
  unsigned short* stk = qkv + (size_t)8 * 24 * 4096 * 32; // 8*4096*256  = 8,388,608
  unsigned short* wq  = stk + (size_t)8 * 4096 * 256;     // 768*256
  unsigned short* wp  = wq  + (size_t)768 * 256;          // 256*256
  unsigned short* y2  = xb;  // alias: xb consumed by qkv_gemm before fcln writes y2

  hipLaunchKernelGGL(cast_w_kernel,    dim3(1280),      dim3(256), 0, stream, qkv_w, proj_w, wq, wp);
  hipLaunchKernelGGL(tcast_kernel,     dim3(64, 4, 8),  dim3(256), 0, stream, x, xb);
  hipLaunchKernelGGL(qkv_gemm_kernel,  dim3(192, 8),    dim3(256), 0, stream, wq, xb, qkv_b, qkv);
  hipLaunchKernelGGL(attn_kernel,      dim3(16, 8, 4),  dim3(256), 0, stream, qkv, stk);
  hipLaunchKernelGGL(fcln_kernel,      dim3(8192),      dim3(256), 0, stream, stk, fc_w, fc_b, ln_g, ln_b, y2);
  hipLaunchKernelGGL(proj_gemm_kernel, dim3(64, 8),     dim3(256), 0, stream, wp, y2, proj_b, out);
}

// Round 2
// 95.383 us; speedup vs baseline: 1.3771x; 1.3771x over previous
//
#include <hip/hip_runtime.h>
#include <stdint.h>

// ---------- types & helpers ----------
typedef __attribute__((ext_vector_type(8))) short bf16x8;   // 8 bf16 (4 VGPRs)
typedef __attribute__((ext_vector_type(4))) float f32x4;    // MFMA accum

#define AS1 __attribute__((address_space(1)))
#define AS3 __attribute__((address_space(3)))

__device__ __forceinline__ void gload_lds16(const void* g, void* l){
  __builtin_amdgcn_global_load_lds((AS1 void*)g, (AS3 void*)l, 16, 0, 0);
}

__device__ __forceinline__ unsigned short to_bf16(float f){
  union { float f; unsigned int i; } x; x.f = f;
  unsigned int u = x.i;
  unsigned int r = (u + 0x7fffu + ((u >> 16) & 1u)) >> 16;   // RNE
  return (unsigned short)r;
}
__device__ __forceinline__ float bf2f(unsigned short s){
  union { unsigned int i; float f; } x; x.i = ((unsigned int)s) << 16; return x.f;
}
__device__ __forceinline__ float bflo(unsigned int u){
  union { unsigned int i; float f; } x; x.i = u << 16; return x.f;
}
__device__ __forceinline__ float bfhi(unsigned int u){
  union { unsigned int i; float f; } x; x.i = u & 0xffff0000u; return x.f;
}
__device__ __forceinline__ void unp8(uint4 v, float* f){
  f[0]=bflo(v.x); f[1]=bfhi(v.x); f[2]=bflo(v.y); f[3]=bfhi(v.y);
  f[4]=bflo(v.z); f[5]=bfhi(v.z); f[6]=bflo(v.w); f[7]=bfhi(v.w);
}

// ---------- K0a: cast weights to bf16 (float4 -> ushort4) ----------
__global__ void cast_w_kernel(const float* __restrict__ qkv_w, const float* __restrict__ proj_w,
                              unsigned short* __restrict__ wq, unsigned short* __restrict__ wp){
  int i = blockIdx.x * 256 + threadIdx.x;          // unit of 4 elements
  const int nq4 = 768 * 256 / 4;
  const int np4 = 256 * 256 / 4;
  if (i < nq4){
    float4 v = ((const float4*)qkv_w)[i];
    ushort4 u; u.x = to_bf16(v.x); u.y = to_bf16(v.y); u.z = to_bf16(v.z); u.w = to_bf16(v.w);
    ((ushort4*)wq)[i] = u;
  } else if (i < nq4 + np4){
    float4 v = ((const float4*)proj_w)[i - nq4];
    ushort4 u; u.x = to_bf16(v.x); u.y = to_bf16(v.y); u.z = to_bf16(v.z); u.w = to_bf16(v.w);
    ((ushort4*)wp)[i - nq4] = u;
  }
}

// ---------- K0b: transpose+cast x (b,c,l) fp32 -> xb (b,l,c) bf16 ----------
__global__ __launch_bounds__(256) void tcast_kernel(const float* __restrict__ x,
                                                    unsigned short* __restrict__ xb){
  __shared__ float tile[64][65];
  int b  = blockIdx.z;
  int c0 = blockIdx.y * 64;
  int l0 = blockIdx.x * 64;
  int tid = threadIdx.x;
  const float* xp = x + ((size_t)b * 256 + c0) * 4096 + l0;
  #pragma unroll
  for (int rep = 0; rep < 4; rep++){
    int idx = rep * 256 + tid;
    int cl = idx >> 4, q4 = idx & 15;
    float4 v = *(const float4*)(xp + (size_t)cl * 4096 + q4 * 4);
    tile[cl][q4 * 4 + 0] = v.x;
    tile[cl][q4 * 4 + 1] = v.y;
    tile[cl][q4 * 4 + 2] = v.z;
    tile[cl][q4 * 4 + 3] = v.w;
  }
  __syncthreads();
  unsigned short* op = xb + ((size_t)b * 4096 + l0) * 256 + c0;
  #pragma unroll
  for (int rep = 0; rep < 4; rep++){
    int idx = rep * 256 + tid;
    int ll = idx >> 4, cp = (idx & 15) * 4;
    ushort4 u;
    u.x = to_bf16(tile[cp + 0][ll]);
    u.y = to_bf16(tile[cp + 1][ll]);
    u.z = to_bf16(tile[cp + 2][ll]);
    u.w = to_bf16(tile[cp + 3][ll]);
    *(ushort4*)(op + (size_t)ll * 256 + cp) = u;
  }
}

// ---------- K1: QKV GEMM  D[o][l] = sum_c Wq[o][c]*X[l][c] (+bias) ----------
// 1-D grid of 1536 blocks; batch = orig&7 so each XCD (i%8 round-robin) owns
// one batch -> its 2MB B-panel stays L2-resident.
__global__ __launch_bounds__(256, 2) void qkv_gemm_kernel(
    const unsigned short* __restrict__ Wq, const unsigned short* __restrict__ xb,
    const float* __restrict__ qkv_b, unsigned short* __restrict__ qkv){
  __shared__ __align__(16) unsigned short lA[128 * 64];
  __shared__ __align__(16) unsigned short lB[128 * 64];
  int orig   = blockIdx.x;
  int b      = orig & 7;           // XCD-pinned batch
  int tile   = orig >> 3;          // 0..191, tile_m innermost (6 consecutive share B)
  int tile_m = tile % 6;
  int tile_n = tile / 6;
  int tid  = threadIdx.x;
  int lane = tid & 63;
  int wave = tid >> 6;
  int m_w = (wave >> 1) * 64;
  int n_w = (wave & 1) * 64;

  f32x4 zero; zero[0]=0.f; zero[1]=0.f; zero[2]=0.f; zero[3]=0.f;
  f32x4 acc[4][4];
  #pragma unroll
  for (int i = 0; i < 4; i++){
    #pragma unroll
    for (int j = 0; j < 4; j++) acc[i][j] = zero;
  }

  const unsigned short* Abase = Wq + (size_t)tile_m * 128 * 256;
  const unsigned short* Bbase = xb + ((size_t)b * 4096 + (size_t)tile_n * 128) * 256;

  for (int ks = 0; ks < 4; ks++){
    int k0 = ks * 64;
    #pragma unroll
    for (int inst = 0; inst < 4; inst++){
      int u    = inst * 256 + tid;      // 16B unit index within tile
      int row  = u >> 3;                // 8 x 16B per 128B row
      int col  = u & 7;
      int scol = col ^ (row & 7);
      unsigned short* ld = lA + inst * 2048 + wave * 512;   // wave-uniform base
      gload_lds16(Abase + (size_t)row * 256 + k0 + scol * 8, ld);
      unsigned short* ldb = lB + inst * 2048 + wave * 512;
      gload_lds16(Bbase + (size_t)row * 256 + k0 + scol * 8, ldb);
    }
    __syncthreads();
    #pragma unroll
    for (int kk = 0; kk < 2; kk++){
      bf16x8 ar[4], br[4];
      #pragma unroll
      for (int i = 0; i < 4; i++){
        int rowa = m_w + i * 16 + (lane & 15);
        int slot = kk * 4 + (lane >> 4);
        ar[i] = *(const bf16x8*)((const char*)lA + rowa * 128 + ((slot ^ (rowa & 7)) << 4));
        int rowb = n_w + i * 16 + (lane & 15);
        br[i] = *(const bf16x8*)((const char*)lB + rowb * 128 + ((slot ^ (rowb & 7)) << 4));
      }
      #pragma unroll
      for (int i = 0; i < 4; i++){
        #pragma unroll
        for (int j = 0; j < 4; j++)
          acc[i][j] = __builtin_amdgcn_mfma_f32_16x16x32_bf16(ar[i], br[j], acc[i][j], 0, 0, 0);
      }
    }
    __syncthreads();
  }

  // epilogue: the 4 accum rows are 4 consecutive o -> one 8B ushort4 store
  #pragma unroll
  for (int i = 0; i < 4; i++){
    #pragma unroll
    for (int j = 0; j < 4; j++){
      int l  = tile_n * 128 + n_w + j * 16 + (lane & 15);
      int o0 = tile_m * 128 + m_w + i * 16 + ((lane >> 4) << 2);
      ushort4 u;
      u.x = to_bf16(acc[i][j][0] + qkv_b[o0 + 0]);
      u.y = to_bf16(acc[i][j][1] + qkv_b[o0 + 1]);
      u.z = to_bf16(acc[i][j][2] + qkv_b[o0 + 2]);
      u.w = to_bf16(acc[i][j][3] + qkv_b[o0 + 3]);
      *(ushort4*)(qkv + ((size_t)(b * 24 + (o0 >> 5)) * 4096 + l) * 32 + (o0 & 31)) = u;
    }
  }
}

// ---------- K2: multi-dilation local attention ----------
// qkv [b][g][l][32], g = s*8 + dil*2 + head ; out stk [b][l][dil][head*32+c] bf16
__global__ __launch_bounds__(256) void attn_kernel(
    const unsigned short* __restrict__ qkv, unsigned short* __restrict__ stk){
  int tid = threadIdx.x;
  int l   = blockIdx.x * 256 + tid;
  int b   = blockIdx.y;
  int di  = blockIdx.z;
  int dil = 1 << di;
  int yy = l >> 6, xx = l & 63;

  #pragma unroll
  for (int head = 0; head < 2; head++){
    size_t gq = ((size_t)(b * 24 +      di * 2 + head) * 4096 + l) * 32;
    size_t gk = ((size_t)(b * 24 +  8 + di * 2 + head) * 4096) * 32;
    size_t gv = ((size_t)(b * 24 + 16 + di * 2 + head) * 4096) * 32;
    float q[32];
    {
      const uint4* p = (const uint4*)(qkv + gq);
      unp8(p[0], q); unp8(p[1], q + 8); unp8(p[2], q + 16); unp8(p[3], q + 24);
    }
    float sc[9]; int nidx[9]; bool ib[9];
    #pragma unroll
    for (int p = 0; p < 9; p++){
      int ny = yy + (p / 3 - 1) * dil;
      int nx = xx + (p % 3 - 1) * dil;
      bool in = ((unsigned)ny < 64u) && ((unsigned)nx < 64u);
      ib[p] = in; nidx[p] = ny * 64 + nx;
      float dot = 0.f;
      if (in){
        const uint4* kp = (const uint4*)(qkv + gk + (size_t)nidx[p] * 32);
        #pragma unroll
        for (int g = 0; g < 4; g++){
          float kf[8]; unp8(kp[g], kf);
          #pragma unroll
          for (int c = 0; c < 8; c++) dot += q[g * 8 + c] * kf[c];
        }
      }
      sc[p] = dot * 0.17677669529663687f;   // HEAD_DIM^-0.5 ; OOB -> exactly 0 (zero-pad)
    }
    float mx = sc[0];
    #pragma unroll
    for (int p = 1; p < 9; p++) mx = fmaxf(mx, sc[p]);
    float w[9]; float den = 0.f;
    #pragma unroll
    for (int p = 0; p < 9; p++){ w[p] = __expf(sc[p] - mx); den += w[p]; }
    float inv = 1.f / den;                   // OOB taps stay in the denominator (zero-pad semantics)
    float o[32];
    #pragma unroll
    for (int c = 0; c < 32; c++) o[c] = 0.f;
    #pragma unroll
    for (int p = 0; p < 9; p++){
      if (ib[p]){
        float wp = w[p] * inv;
        const uint4* vp = (const uint4*)(qkv + gv + (size_t)nidx[p] * 32);
        #pragma unroll
        for (int g = 0; g < 4; g++){
          float vf[8]; unp8(vp[g], vf);
          #pragma unroll
          for (int c = 0; c < 8; c++) o[g * 8 + c] += wp * vf[c];
        }
      }
    }
    unsigned short* op = stk + ((size_t)(b * 4096 + l) * 4 + di) * 64 + head * 32;
    #pragma unroll
    for (int g = 0; g < 4; g++){
      uint4 u;
      u.x = (unsigned)to_bf16(o[g*8+0]) | ((unsigned)to_bf16(o[g*8+1]) << 16);
      u.y = (unsigned)to_bf16(o[g*8+2]) | ((unsigned)to_bf16(o[g*8+3]) << 16);
      u.z = (unsigned)to_bf16(o[g*8+4]) | ((unsigned)to_bf16(o[g*8+5]) << 16);
      u.w = (unsigned)to_bf16(o[g*8+6]) | ((unsigned)to_bf16(o[g*8+7]) << 16);
      ((uint4*)op)[g] = u;
    }
  }
}

// ---------- K3: fc(4x4)+residual+LayerNorm(64) ; 1 wave = 1 pixel ----------
__global__ __launch_bounds__(256) void fcln_kernel(
    const unsigned short* __restrict__ stk,
    const float* __restrict__ fc_w, const float* __restrict__ fc_b,
    const float* __restrict__ ln_g, const float* __restrict__ ln_b,
    unsigned short* __restrict__ y2){
  int tid = threadIdx.x;
  int pix = blockIdx.x * 4 + (tid >> 6);
  int c   = tid & 63;
  const unsigned short* sp = stk + (size_t)pix * 256;
  float st[4];
  #pragma unroll
  for (int s = 0; s < 4; s++) st[s] = bf2f(sp[s * 64 + c]);
  float fused[4];
  #pragma unroll
  for (int t = 0; t < 4; t++){
    float f = fc_b[t] + st[t];
    #pragma unroll
    for (int s = 0; s < 4; s++) f += fc_w[t * 4 + s] * st[s];
    fused[t] = f;
  }
  float g = ln_g[c], bb = ln_b[c];
  unsigned short* op = y2 + (size_t)pix * 256;
  #pragma unroll
  for (int t = 0; t < 4; t++){
    float v = fused[t];
    float s1 = v, s2 = v * v;
    #pragma unroll
    for (int m = 1; m < 64; m <<= 1){ s1 += __shfl_xor(s1, m); s2 += __shfl_xor(s2, m); }
    float mu  = s1 * 0.015625f;
    float var = s2 * 0.015625f - mu * mu;
    float rs  = rsqrtf(var + 1e-5f);
    op[t * 64 + c] = to_bf16((v - mu) * rs * g + bb);
  }
}

// ---------- K4: proj GEMM  out[b][o][l] = sum_ch Wp[o][ch]*y2[b][l][ch] + pb ----------
__global__ __launch_bounds__(256, 2) void proj_gemm_kernel(
    const unsigned short* __restrict__ Wp, const unsigned short* __restrict__ y2,
    const float* __restrict__ proj_b, float* __restrict__ out){
  __shared__ __align__(16) unsigned short lA[128 * 64];
  __shared__ __align__(16) unsigned short lB[128 * 64];
  int orig   = blockIdx.x;
  int b      = orig & 7;           // XCD-pinned batch
  int tile   = orig >> 3;          // 0..63, tile_m innermost
  int tile_m = tile & 1;
  int tile_n = tile >> 1;
  int tid  = threadIdx.x;
  int lane = tid & 63;
  int wave = tid >> 6;
  int m_w = (wave >> 1) * 64;
  int n_w = (wave & 1) * 64;

  f32x4 zero; zero[0]=0.f; zero[1]=0.f; zero[2]=0.f; zero[3]=0.f;
  f32x4 acc[4][4];
  #pragma unroll
  for (int i = 0; i < 4; i++){
    #pragma unroll
    for (int j = 0; j < 4; j++) acc[i][j] = zero;
  }

  const unsigned short* Abase = Wp + (size_t)tile_m * 128 * 256;
  const unsigned short* Bbase = y2 + ((size_t)b * 4096 + (size_t)tile_n * 128) * 256;

  for (int ks = 0; ks < 4; ks++){
    int k0 = ks * 64;
    #pragma unroll
    for (int inst = 0; inst < 4; inst++){
      int u    = inst * 256 + tid;
      int row  = u >> 3;
      int col  = u & 7;
      int scol = col ^ (row & 7);
      unsigned short* ld = lA + inst * 2048 + wave * 512;
      gload_lds16(Abase + (size_t)row * 256 + k0 + scol * 8, ld);
      unsigned short* ldb = lB + inst * 2048 + wave * 512;
      gload_lds16(Bbase + (size_t)row * 256 + k0 + scol * 8, ldb);
    }
    __syncthreads();
    #pragma unroll
    for (int kk = 0; kk < 2; kk++){
      bf16x8 ar[4], br[4];
      #pragma unroll
      for (int i = 0; i < 4; i++){
        int rowa = m_w + i * 16 + (lane & 15);
        int slot = kk * 4 + (lane >> 4);
        ar[i] = *(const bf16x8*)((const char*)lA + rowa * 128 + ((slot ^ (rowa & 7)) << 4));
        int rowb = n_w + i * 16 + (lane & 15);
        br[i] = *(const bf16x8*)((const char*)lB + rowb * 128 + ((slot ^ (rowb & 7)) << 4));
      }
      #pragma unroll
      for (int i = 0; i < 4; i++){
        #pragma unroll
        for (int j = 0; j < 4; j++)
          acc[i][j] = __builtin_amdgcn_mfma_f32_16x16x32_bf16(ar[i], br[j], acc[i][j], 0, 0, 0);
      }
    }
    __syncthreads();
  }

  #pragma unroll
  for (int i = 0; i < 4; i++){
    #pragma unroll
    for (int j = 0; j < 4; j++){
      int l = tile_n * 128 + n_w + j * 16 + (lane & 15);
      #pragma unroll
      for (int r = 0; r < 4; r++){
        int o = tile_m * 128 + m_w + i * 16 + ((lane >> 4) << 2) + r;
        out[((size_t)b * 256 + o) * 4096 + l] = acc[i][j][r] + proj_b[o];
      }
    }
  }
}

// ---------- launch ----------
extern "C" void kernel_launch(void* const* d_in, const int* in_sizes, int n_in,
                              void* d_out, int out_size, void* d_ws, size_t ws_size,
                              hipStream_t stream){
  const float* x      = (const float*)d_in[0];
  const float* qkv_w  = (const float*)d_in[1];
  const float* qkv_b  = (const float*)d_in[2];
  const float* fc_w   = (const float*)d_in[3];
  const float* fc_b   = (const float*)d_in[4];
  const float* ln_g   = (const float*)d_in[5];
  const float* ln_b   = (const float*)d_in[6];
  const float* proj_w = (const float*)d_in[7];
  const float* proj_b = (const float*)d_in[8];
  float* out = (float*)d_out;

  // workspace layout (bf16 elements)
  unsigned short* xb  = (unsigned short*)d_ws;            // 8*4096*256  = 8,388,608
  unsigned short* qkv = xb  + (size_t)8 * 4096 * 256;     // 8*24*4096*32 = 25,165,824
  unsigned short* stk = qkv + (size_t)8 * 24 * 4096 * 32; // 8*4096*256  = 8,388,608
  unsigned short* wq  = stk + (size_t)8 * 4096 * 256;     // 768*256
  unsigned short* wp  = wq  + (size_t)768 * 256;          // 256*256
  unsigned short* y2  = xb;  // alias: xb consumed by qkv_gemm before fcln writes y2

  hipLaunchKernelGGL(cast_w_kernel,    dim3(256),       dim3(256), 0, stream, qkv_w, proj_w, wq, wp);
  hipLaunchKernelGGL(tcast_kernel,     dim3(64, 4, 8),  dim3(256), 0, stream, x, xb);
  hipLaunchKernelGGL(qkv_gemm_kernel,  dim3(1536),      dim3(256), 0, stream, wq, xb, qkv_b, qkv);
  hipLaunchKernelGGL(attn_kernel,      dim3(16, 8, 4),  dim3(256), 0, stream, qkv, stk);
  hipLaunchKernelGGL(fcln_kernel,      dim3(8192),      dim3(256), 0, stream, stk, fc_w, fc_b, ln_g, ln_b, y2);
  hipLaunchKernelGGL(proj_gemm_kernel, dim3(512),       dim3(256), 0, stream, wp, y2, proj_b, out);
}

// Round 3
// 91.715 us; speedup vs baseline: 1.4322x; 1.0400x over previous
//
#include <hip/hip_runtime.h>
#include <stdint.h>

// ---------- types & helpers ----------
typedef __attribute__((ext_vector_type(8))) short bf16x8;   // 8 bf16 (4 VGPRs)
typedef __attribute__((ext_vector_type(4))) float f32x4;    // MFMA accum

#define AS1 __attribute__((address_space(1)))
#define AS3 __attribute__((address_space(3)))

__device__ __forceinline__ void gload_lds16(const void* g, void* l){
  __builtin_amdgcn_global_load_lds((AS1 void*)g, (AS3 void*)l, 16, 0, 0);
}

__device__ __forceinline__ unsigned short to_bf16(float f){
  union { float f; unsigned int i; } x; x.f = f;
  unsigned int u = x.i;
  unsigned int r = (u + 0x7fffu + ((u >> 16) & 1u)) >> 16;   // RNE
  return (unsigned short)r;
}
__device__ __forceinline__ float bf2f(unsigned short s){
  union { unsigned int i; float f; } x; x.i = ((unsigned int)s) << 16; return x.f;
}
__device__ __forceinline__ float bflo(unsigned int u){
  union { unsigned int i; float f; } x; x.i = u << 16; return x.f;
}
__device__ __forceinline__ float bfhi(unsigned int u){
  union { unsigned int i; float f; } x; x.i = u & 0xffff0000u; return x.f;
}
__device__ __forceinline__ void unp8(uint4 v, float* f){
  f[0]=bflo(v.x); f[1]=bfhi(v.x); f[2]=bflo(v.y); f[3]=bfhi(v.y);
  f[4]=bflo(v.z); f[5]=bfhi(v.z); f[6]=bflo(v.w); f[7]=bfhi(v.w);
}

// ---------- K0a: cast weights to bf16 (float4 -> ushort4) ----------
__global__ void cast_w_kernel(const float* __restrict__ qkv_w, const float* __restrict__ proj_w,
                              unsigned short* __restrict__ wq, unsigned short* __restrict__ wp){
  int i = blockIdx.x * 256 + threadIdx.x;          // unit of 4 elements
  const int nq4 = 768 * 256 / 4;
  const int np4 = 256 * 256 / 4;
  if (i < nq4){
    float4 v = ((const float4*)qkv_w)[i];
    ushort4 u; u.x = to_bf16(v.x); u.y = to_bf16(v.y); u.z = to_bf16(v.z); u.w = to_bf16(v.w);
    ((ushort4*)wq)[i] = u;
  } else if (i < nq4 + np4){
    float4 v = ((const float4*)proj_w)[i - nq4];
    ushort4 u; u.x = to_bf16(v.x); u.y = to_bf16(v.y); u.z = to_bf16(v.z); u.w = to_bf16(v.w);
    ((ushort4*)wp)[i - nq4] = u;
  }
}

// ---------- K0b: transpose+cast x (b,c,l) fp32 -> xb (b,l,c) bf16 ----------
__global__ __launch_bounds__(256) void tcast_kernel(const float* __restrict__ x,
                                                    unsigned short* __restrict__ xb){
  __shared__ float tile[64][65];
  int b  = blockIdx.z;
  int c0 = blockIdx.y * 64;
  int l0 = blockIdx.x * 64;
  int tid = threadIdx.x;
  const float* xp = x + ((size_t)b * 256 + c0) * 4096 + l0;
  #pragma unroll
  for (int rep = 0; rep < 4; rep++){
    int idx = rep * 256 + tid;
    int cl = idx >> 4, q4 = idx & 15;
    float4 v = *(const float4*)(xp + (size_t)cl * 4096 + q4 * 4);
    tile[cl][q4 * 4 + 0] = v.x;
    tile[cl][q4 * 4 + 1] = v.y;
    tile[cl][q4 * 4 + 2] = v.z;
    tile[cl][q4 * 4 + 3] = v.w;
  }
  __syncthreads();
  unsigned short* op = xb + ((size_t)b * 4096 + l0) * 256 + c0;
  #pragma unroll
  for (int rep = 0; rep < 4; rep++){
    int idx = rep * 256 + tid;
    int ll = idx >> 4, cp = (idx & 15) * 4;
    ushort4 u;
    u.x = to_bf16(tile[cp + 0][ll]);
    u.y = to_bf16(tile[cp + 1][ll]);
    u.z = to_bf16(tile[cp + 2][ll]);
    u.w = to_bf16(tile[cp + 3][ll]);
    *(ushort4*)(op + (size_t)ll * 256 + cp) = u;
  }
}

// ---------- K1: QKV GEMM  D[o][l] = sum_c Wq[o][c]*X[l][c] (+bias) ----------
// 1-D grid of 1536 blocks; batch = orig&7 so each XCD (i%8 round-robin) owns
// one batch -> its 2MB B-panel stays L2-resident.
__global__ __launch_bounds__(256, 2) void qkv_gemm_kernel(
    const unsigned short* __restrict__ Wq, const unsigned short* __restrict__ xb,
    const float* __restrict__ qkv_b, unsigned short* __restrict__ qkv){
  __shared__ __align__(16) unsigned short lA[128 * 64];
  __shared__ __align__(16) unsigned short lB[128 * 64];
  int orig   = blockIdx.x;
  int b      = orig & 7;           // XCD-pinned batch
  int tile   = orig >> 3;          // 0..191, tile_m innermost (6 consecutive share B)
  int tile_m = tile % 6;
  int tile_n = tile / 6;
  int tid  = threadIdx.x;
  int lane = tid & 63;
  int wave = tid >> 6;
  int m_w = (wave >> 1) * 64;
  int n_w = (wave & 1) * 64;

  f32x4 zero; zero[0]=0.f; zero[1]=0.f; zero[2]=0.f; zero[3]=0.f;
  f32x4 acc[4][4];
  #pragma unroll
  for (int i = 0; i < 4; i++){
    #pragma unroll
    for (int j = 0; j < 4; j++) acc[i][j] = zero;
  }

  const unsigned short* Abase = Wq + (size_t)tile_m * 128 * 256;
  const unsigned short* Bbase = xb + ((size_t)b * 4096 + (size_t)tile_n * 128) * 256;

  for (int ks = 0; ks < 4; ks++){
    int k0 = ks * 64;
    #pragma unroll
    for (int inst = 0; inst < 4; inst++){
      int u    = inst * 256 + tid;      // 16B unit index within tile
      int row  = u >> 3;                // 8 x 16B per 128B row
      int col  = u & 7;
      int scol = col ^ (row & 7);
      unsigned short* ld = lA + inst * 2048 + wave * 512;   // wave-uniform base
      gload_lds16(Abase + (size_t)row * 256 + k0 + scol * 8, ld);
      unsigned short* ldb = lB + inst * 2048 + wave * 512;
      gload_lds16(Bbase + (size_t)row * 256 + k0 + scol * 8, ldb);
    }
    __syncthreads();
    #pragma unroll
    for (int kk = 0; kk < 2; kk++){
      bf16x8 ar[4], br[4];
      #pragma unroll
      for (int i = 0; i < 4; i++){
        int rowa = m_w + i * 16 + (lane & 15);
        int slot = kk * 4 + (lane >> 4);
        ar[i] = *(const bf16x8*)((const char*)lA + rowa * 128 + ((slot ^ (rowa & 7)) << 4));
        int rowb = n_w + i * 16 + (lane & 15);
        br[i] = *(const bf16x8*)((const char*)lB + rowb * 128 + ((slot ^ (rowb & 7)) << 4));
      }
      #pragma unroll
      for (int i = 0; i < 4; i++){
        #pragma unroll
        for (int j = 0; j < 4; j++)
          acc[i][j] = __builtin_amdgcn_mfma_f32_16x16x32_bf16(ar[i], br[j], acc[i][j], 0, 0, 0);
      }
    }
    __syncthreads();
  }

  // epilogue: the 4 accum rows are 4 consecutive o -> one 8B ushort4 store
  #pragma unroll
  for (int i = 0; i < 4; i++){
    #pragma unroll
    for (int j = 0; j < 4; j++){
      int l  = tile_n * 128 + n_w + j * 16 + (lane & 15);
      int o0 = tile_m * 128 + m_w + i * 16 + ((lane >> 4) << 2);
      ushort4 u;
      u.x = to_bf16(acc[i][j][0] + qkv_b[o0 + 0]);
      u.y = to_bf16(acc[i][j][1] + qkv_b[o0 + 1]);
      u.z = to_bf16(acc[i][j][2] + qkv_b[o0 + 2]);
      u.w = to_bf16(acc[i][j][3] + qkv_b[o0 + 3]);
      *(ushort4*)(qkv + ((size_t)(b * 24 + (o0 >> 5)) * 4096 + l) * 32 + (o0 & 31)) = u;
    }
  }
}

// ---------- K2: multi-dilation local attention (coalesced, 4 lanes/pixel) ----------
// qkv [b][g][l][32], g = s*8 + dil*2 + head ; out stk [b][l][dil][head*32+c] bf16
// Thread tid: lc = tid&3 owns 8 channels (16B); pl = tid>>2 is pixel-in-block.
// A wave covers 16 consecutive pixels -> every tap load is a contiguous 1KB
// wave transaction. Dot finished with 2 shfl_xor within the 4-lane group.
__global__ __launch_bounds__(256) void attn_kernel(
    const unsigned short* __restrict__ qkv, unsigned short* __restrict__ stk){
  int tid = threadIdx.x;
  int lc  = tid & 3;
  int pl  = tid >> 2;
  int l   = blockIdx.x * 64 + pl;
  int b   = blockIdx.y;
  int di  = blockIdx.z;
  int dil = 1 << di;
  int yy = l >> 6, xx = l & 63;

  #pragma unroll
  for (int head = 0; head < 2; head++){
    const unsigned short* qp = qkv + ((size_t)(b * 24 +      di * 2 + head) * 4096 + l) * 32 + lc * 8;
    const unsigned short* kb = qkv + ((size_t)(b * 24 +  8 + di * 2 + head) * 4096) * 32;
    const unsigned short* vb = qkv + ((size_t)(b * 24 + 16 + di * 2 + head) * 4096) * 32;
    float qf[8];
    unp8(*(const uint4*)qp, qf);

    float sc[9]; int nidx[9]; bool ib[9];
    #pragma unroll
    for (int p = 0; p < 9; p++){
      int ny = yy + (p / 3 - 1) * dil;
      int nx = xx + (p % 3 - 1) * dil;
      bool in = ((unsigned)ny < 64u) && ((unsigned)nx < 64u);   // uniform across the 4-lane group
      ib[p] = in; nidx[p] = ny * 64 + nx;
      float part = 0.f;
      if (in){
        float kf[8];
        unp8(*(const uint4*)(kb + (size_t)nidx[p] * 32 + lc * 8), kf);
        #pragma unroll
        for (int c = 0; c < 8; c++) part += qf[c] * kf[c];
      }
      part += __shfl_xor(part, 1);
      part += __shfl_xor(part, 2);
      sc[p] = part * 0.17677669529663687f;   // OOB -> exactly 0 (zero-pad semantics)
    }
    float mx = sc[0];
    #pragma unroll
    for (int p = 1; p < 9; p++) mx = fmaxf(mx, sc[p]);
    float w[9]; float den = 0.f;
    #pragma unroll
    for (int p = 0; p < 9; p++){ w[p] = __expf(sc[p] - mx); den += w[p]; }
    float inv = 1.f / den;                   // OOB taps stay in the denominator

    float o[8];
    #pragma unroll
    for (int c = 0; c < 8; c++) o[c] = 0.f;
    #pragma unroll
    for (int p = 0; p < 9; p++){
      if (ib[p]){
        float wp = w[p] * inv;
        float vf[8];
        unp8(*(const uint4*)(vb + (size_t)nidx[p] * 32 + lc * 8), vf);
        #pragma unroll
        for (int c = 0; c < 8; c++) o[c] += wp * vf[c];
      }
    }
    unsigned short* op = stk + ((size_t)(b * 4096 + l) * 4 + di) * 64 + head * 32 + lc * 8;
    uint4 u;
    u.x = (unsigned)to_bf16(o[0]) | ((unsigned)to_bf16(o[1]) << 16);
    u.y = (unsigned)to_bf16(o[2]) | ((unsigned)to_bf16(o[3]) << 16);
    u.z = (unsigned)to_bf16(o[4]) | ((unsigned)to_bf16(o[5]) << 16);
    u.w = (unsigned)to_bf16(o[6]) | ((unsigned)to_bf16(o[7]) << 16);
    *(uint4*)op = u;
  }
}

// ---------- K3: fc(4x4)+residual+LayerNorm(64) ; 1 wave = 1 pixel ----------
__global__ __launch_bounds__(256) void fcln_kernel(
    const unsigned short* __restrict__ stk,
    const float* __restrict__ fc_w, const float* __restrict__ fc_b,
    const float* __restrict__ ln_g, const float* __restrict__ ln_b,
    unsigned short* __restrict__ y2){
  int tid = threadIdx.x;
  int pix = blockIdx.x * 4 + (tid >> 6);
  int c   = tid & 63;
  const unsigned short* sp = stk + (size_t)pix * 256;
  float st[4];
  #pragma unroll
  for (int s = 0; s < 4; s++) st[s] = bf2f(sp[s * 64 + c]);
  float fused[4];
  #pragma unroll
  for (int t = 0; t < 4; t++){
    float f = fc_b[t] + st[t];
    #pragma unroll
    for (int s = 0; s < 4; s++) f += fc_w[t * 4 + s] * st[s];
    fused[t] = f;
  }
  float g = ln_g[c], bb = ln_b[c];
  unsigned short* op = y2 + (size_t)pix * 256;
  #pragma unroll
  for (int t = 0; t < 4; t++){
    float v = fused[t];
    float s1 = v, s2 = v * v;
    #pragma unroll
    for (int m = 1; m < 64; m <<= 1){ s1 += __shfl_xor(s1, m); s2 += __shfl_xor(s2, m); }
    float mu  = s1 * 0.015625f;
    float var = s2 * 0.015625f - mu * mu;
    float rs  = rsqrtf(var + 1e-5f);
    op[t * 64 + c] = to_bf16((v - mu) * rs * g + bb);
  }
}

// ---------- K4: proj GEMM  out[b][o][l] = sum_ch Wp[o][ch]*y2[b][l][ch] + pb ----------
__global__ __launch_bounds__(256, 2) void proj_gemm_kernel(
    const unsigned short* __restrict__ Wp, const unsigned short* __restrict__ y2,
    const float* __restrict__ proj_b, float* __restrict__ out){
  __shared__ __align__(16) unsigned short lA[128 * 64];
  __shared__ __align__(16) unsigned short lB[128 * 64];
  int orig   = blockIdx.x;
  int b      = orig & 7;           // XCD-pinned batch
  int tile   = orig >> 3;          // 0..63, tile_m innermost
  int tile_m = tile & 1;
  int tile_n = tile >> 1;
  int tid  = threadIdx.x;
  int lane = tid & 63;
  int wave = tid >> 6;
  int m_w = (wave >> 1) * 64;
  int n_w = (wave & 1) * 64;

  f32x4 zero; zero[0]=0.f; zero[1]=0.f; zero[2]=0.f; zero[3]=0.f;
  f32x4 acc[4][4];
  #pragma unroll
  for (int i = 0; i < 4; i++){
    #pragma unroll
    for (int j = 0; j < 4; j++) acc[i][j] = zero;
  }

  const unsigned short* Abase = Wp + (size_t)tile_m * 128 * 256;
  const unsigned short* Bbase = y2 + ((size_t)b * 4096 + (size_t)tile_n * 128) * 256;

  for (int ks = 0; ks < 4; ks++){
    int k0 = ks * 64;
    #pragma unroll
    for (int inst = 0; inst < 4; inst++){
      int u    = inst * 256 + tid;
      int row  = u >> 3;
      int col  = u & 7;
      int scol = col ^ (row & 7);
      unsigned short* ld = lA + inst * 2048 + wave * 512;
      gload_lds16(Abase + (size_t)row * 256 + k0 + scol * 8, ld);
      unsigned short* ldb = lB + inst * 2048 + wave * 512;
      gload_lds16(Bbase + (size_t)row * 256 + k0 + scol * 8, ldb);
    }
    __syncthreads();
    #pragma unroll
    for (int kk = 0; kk < 2; kk++){
      bf16x8 ar[4], br[4];
      #pragma unroll
      for (int i = 0; i < 4; i++){
        int rowa = m_w + i * 16 + (lane & 15);
        int slot = kk * 4 + (lane >> 4);
        ar[i] = *(const bf16x8*)((const char*)lA + rowa * 128 + ((slot ^ (rowa & 7)) << 4));
        int rowb = n_w + i * 16 + (lane & 15);
        br[i] = *(const bf16x8*)((const char*)lB + rowb * 128 + ((slot ^ (rowb & 7)) << 4));
      }
      #pragma unroll
      for (int i = 0; i < 4; i++){
        #pragma unroll
        for (int j = 0; j < 4; j++)
          acc[i][j] = __builtin_amdgcn_mfma_f32_16x16x32_bf16(ar[i], br[j], acc[i][j], 0, 0, 0);
      }
    }
    __syncthreads();
  }

  #pragma unroll
  for (int i = 0; i < 4; i++){
    #pragma unroll
    for (int j = 0; j < 4; j++){
      int l = tile_n * 128 + n_w + j * 16 + (lane & 15);
      #pragma unroll
      for (int r = 0; r < 4; r++){
        int o = tile_m * 128 + m_w + i * 16 + ((lane >> 4) << 2) + r;
        out[((size_t)b * 256 + o) * 4096 + l] = acc[i][j][r] + proj_b[o];
      }
    }
  }
}

// ---------- launch ----------
extern "C" void kernel_launch(void* const* d_in, const int* in_sizes, int n_in,
                              void* d_out, int out_size, void* d_ws, size_t ws_size,
                              hipStream_t stream){
  const float* x      = (const float*)d_in[0];
  const float* qkv_w  = (const float*)d_in[1];
  const float* qkv_b  = (const float*)d_in[2];
  const float* fc_w   = (const float*)d_in[3];
  const float* fc_b   = (const float*)d_in[4];
  const float* ln_g   = (const float*)d_in[5];
  const float* ln_b   = (const float*)d_in[6];
  const float* proj_w = (const float*)d_in[7];
  const float* proj_b = (const float*)d_in[8];
  float* out = (float*)d_out;

  // workspace layout (bf16 elements)
  unsigned short* xb  = (unsigned short*)d_ws;            // 8*4096*256  = 8,388,608
  unsigned short* qkv = xb  + (size_t)8 * 4096 * 256;     // 8*24*4096*32 = 25,165,824
  unsigned short* stk = qkv + (size_t)8 * 24 * 4096 * 32; // 8*4096*256  = 8,388,608
  unsigned short* wq  = stk + (size_t)8 * 4096 * 256;     // 768*256
  unsigned short* wp  = wq  + (size_t)768 * 256;          // 256*256
  unsigned short* y2  = xb;  // alias: xb consumed by qkv_gemm before fcln writes y2

  hipLaunchKernelGGL(cast_w_kernel,    dim3(256),       dim3(256), 0, stream, qkv_w, proj_w, wq, wp);
  hipLaunchKernelGGL(tcast_kernel,     dim3(64, 4, 8),  dim3(256), 0, stream, x, xb);
  hipLaunchKernelGGL(qkv_gemm_kernel,  dim3(1536),      dim3(256), 0, stream, wq, xb, qkv_b, qkv);
  hipLaunchKernelGGL(attn_kernel,      dim3(64, 8, 4),  dim3(256), 0, stream, qkv, stk);
  hipLaunchKernelGGL(fcln_kernel,      dim3(8192),      dim3(256), 0, stream, stk, fc_w, fc_b, ln_g, ln_b, y2);
  hipLaunchKernelGGL(proj_gemm_kernel, dim3(512),       dim3(256), 0, stream, wp, y2, proj_b, out);
}